// Round 3
// baseline (207.253 us; speedup 1.0000x reference)
//
#include <hip/hip_runtime.h>
#include <cmath>

// MHSA cosine-attention block, MI355X/gfx950.  Round 3.
// K1: QKV projections, FULLY UNROLLED (no dynamic reg-array indexing -> no
//     scratch spill). 3-part grid (Q|K|V). Q/K k8-tiled bf16, V as [nh][v][l].
// K2: flash attention, S^T = K Q^T, packed ds_write_b64 P rows, 32 q/wave,
//     grid (32,4,8) = 4096 waves (4/SIMD @ launch_bounds(256,4)).
// K3: coalesced reduce of numP, fp32 SIMT output projection + residual.

typedef __bf16 bf16x8 __attribute__((ext_vector_type(8)));
typedef __bf16 bf16x4 __attribute__((ext_vector_type(4)));
typedef float f4_t __attribute__((ext_vector_type(4)));

#define LQ 4096       // sequence length H*W
#define NH 4          // n*heads
#define KS 8          // key splits

__device__ inline f4_t mfma16(bf16x8 a, bf16x8 b, f4_t c) {
    return __builtin_amdgcn_mfma_f32_16x16x32_bf16(a, b, c, 0, 0, 0);
}

// ---------------------------------------------------------------------------
// Kernel 1: QKV projection + normalize.
// grid: dim3(3, 64, 2) = (part: 0=Q,1=K,2=V) x (l-tile of 64) x n.
// block: 128 thr (2 waves). lane = l. part<2: wave = head, thread computes
// the full dk=64 vector (per-thread L2 norm). part==2: wave = head, thread
// computes 32 V channels. ALL loops fully unrolled -> arrays stay in VGPRs.
// ---------------------------------------------------------------------------
__global__ __launch_bounds__(128, 2) void k1_qkv(
        const float* __restrict__ x,
        const float* __restrict__ Wq, const float* __restrict__ bq,
        const float* __restrict__ Wk, const float* __restrict__ bk,
        const float* __restrict__ Wv, const float* __restrict__ bv,
        __bf16* __restrict__ Qb, __bf16* __restrict__ Kb,
        __bf16* __restrict__ Vtb) {
    const int lane = threadIdx.x & 63;
    const int w    = threadIdx.x >> 6;       // head
    const int part = blockIdx.x;             // 0=Q, 1=K, 2=V
    const int lt   = blockIdx.y;
    const int n    = blockIdx.z;
    const int l    = lt * 64 + lane;

    // x column -> 64 VGPRs (lane-contiguous per c: coalesced)
    float xv[64];
    const float* xp = x + (size_t)n * 64 * LQ + l;
#pragma unroll
    for (int c = 0; c < 64; ++c) xv[c] = xp[(size_t)c * LQ];

    if (part < 2) {
        const float* W  = part ? Wk : Wq;
        const float* bb = part ? bk : bq;
        __bf16* dst     = part ? Kb : Qb;
        const int nh    = n * 2 + w;

        float acc[64];
#pragma unroll
        for (int k = 0; k < 64; ++k) {
            const float* wr = W + (size_t)(w * 64 + k) * 64;
            float a = bb[w * 64 + k];
#pragma unroll
            for (int c4 = 0; c4 < 16; ++c4) {
                f4_t t = *(const f4_t*)(wr + c4 * 4);   // wave-uniform -> s_load
                a = fmaf(t[0], xv[c4 * 4 + 0], a);
                a = fmaf(t[1], xv[c4 * 4 + 1], a);
                a = fmaf(t[2], xv[c4 * 4 + 2], a);
                a = fmaf(t[3], xv[c4 * 4 + 3], a);
            }
            acc[k] = a;
        }

        float ss = 0.f;
#pragma unroll
        for (int k = 0; k < 64; ++k) ss = fmaf(acc[k], acc[k], ss);
        const float rn = 1.0f / fmaxf(sqrtf(ss), 1e-6f);

        // k8-tiled store: dst[((nh*8 + kc)*LQ + l)*8 + j] -- 16B/lane contiguous
#pragma unroll
        for (int kc = 0; kc < 8; ++kc) {
            bf16x8 v8;
#pragma unroll
            for (int j = 0; j < 8; ++j) v8[j] = (__bf16)(acc[kc * 8 + j] * rn);
            *(bf16x8*)(dst + ((size_t)(nh * 8 + kc) * LQ + l) * 8) = v8;
        }
    } else {
        const int h = w;
        float acc[32];
#pragma unroll
        for (int v = 0; v < 32; ++v) {
            const float* wr = Wv + (size_t)(h * 32 + v) * 64;
            float a = bv[h * 32 + v];
#pragma unroll
            for (int c4 = 0; c4 < 16; ++c4) {
                f4_t t = *(const f4_t*)(wr + c4 * 4);
                a = fmaf(t[0], xv[c4 * 4 + 0], a);
                a = fmaf(t[1], xv[c4 * 4 + 1], a);
                a = fmaf(t[2], xv[c4 * 4 + 2], a);
                a = fmaf(t[3], xv[c4 * 4 + 3], a);
            }
            acc[v] = a;
        }
#pragma unroll
        for (int v = 0; v < 32; ++v)
            Vtb[(size_t)((n * 2 + h) * 32 + v) * LQ + l] = (__bf16)acc[v];
    }
}

// ---------------------------------------------------------------------------
// Kernel 2: flash attention (scores in [-1,1], no max tracking).
// grid: (32 q-blocks of 128, nh=4, ks=8) = 1024 blocks x 4 waves = 4096 waves.
// wave owns 32 q; 16 chunks of 32 keys.
// S^T = K Q^T  =>  C lane holds 4 consecutive KEYS for one q  =>  P row
// writes pack to ds_write_b64; PV B-frag read is ds_read_b128.
// ---------------------------------------------------------------------------
__global__ __launch_bounds__(256, 4) void k2_attn(
        const __bf16* __restrict__ Qb, const __bf16* __restrict__ Kb,
        const __bf16* __restrict__ Vtb,
        float* __restrict__ numP, float* __restrict__ denP) {
    const int lane = threadIdx.x & 63;
    const int wave = threadIdx.x >> 6;
    const int quad = lane >> 4;
    const int l15  = lane & 15;
    const int nh   = blockIdx.y;
    const int ks   = blockIdx.z;
    const int qbase = blockIdx.x * 128 + wave * 32;
    const int kbase = ks * 512;

    __shared__ __bf16 P[4][2][16][40];   // [wave][qt][q-row][32 keys + pad]

    const f4_t fzero = {0.f, 0.f, 0.f, 0.f};

    // Q fragments (k8-tiled layout), reused for all 512 keys
    bf16x8 qf[2][2];
#pragma unroll
    for (int qt = 0; qt < 2; ++qt)
#pragma unroll
        for (int kh = 0; kh < 2; ++kh)
            qf[qt][kh] = *(const bf16x8*)(Qb +
                ((size_t)(nh * 8 + kh * 4 + quad) * LQ + qbase + qt * 16 + l15) * 8);

    f4_t racc[2][2];                     // [vt][qt]: (v=quad*4+r+vt*16, q=l15+qt*16)
#pragma unroll
    for (int a = 0; a < 2; ++a)
#pragma unroll
        for (int b = 0; b < 2; ++b) racc[a][b] = fzero;
    float den[2] = {0.f, 0.f};

    for (int ch = 0; ch < 16; ++ch) {
        const int kb = kbase + ch * 32;

        bf16x8 kf[2][2], vf[2];
#pragma unroll
        for (int kt = 0; kt < 2; ++kt)
#pragma unroll
            for (int kh = 0; kh < 2; ++kh)
                kf[kt][kh] = *(const bf16x8*)(Kb +
                    ((size_t)(nh * 8 + kh * 4 + quad) * LQ + kb + kt * 16 + l15) * 8);
#pragma unroll
        for (int vt = 0; vt < 2; ++vt)
            vf[vt] = *(const bf16x8*)(Vtb +
                (size_t)(nh * 32 + vt * 16 + l15) * LQ + kb + quad * 8);

#pragma unroll
        for (int qt = 0; qt < 2; ++qt) {
#pragma unroll
            for (int kt = 0; kt < 2; ++kt) {
                // S^T tile: m = key (quad*4+r), n = q (l15)
                f4_t s = mfma16(kf[kt][0], qf[qt][0], fzero);
                s      = mfma16(kf[kt][1], qf[qt][1], s);
                bf16x4 pv;
                float d = 0.f;
#pragma unroll
                for (int r = 0; r < 4; ++r) {
                    float p = __expf(s[r]);
                    d += p;
                    pv[r] = (__bf16)p;
                }
                den[qt] += d;
                *(bf16x4*)&P[wave][qt][l15][kt * 16 + quad * 4] = pv;  // b64 packed
            }
            // PV: A = V^T rows (key-major), B = P rows (key-major)
            bf16x8 pf = *(const bf16x8*)&P[wave][qt][l15][quad * 8];   // b128
#pragma unroll
            for (int vt = 0; vt < 2; ++vt)
                racc[vt][qt] = mfma16(vf[vt], pf, racc[vt][qt]);
        }
    }

    // den: reduce quad partials (same q = l15 across quads)
#pragma unroll
    for (int qt = 0; qt < 2; ++qt) {
        den[qt] += __shfl_xor(den[qt], 16, 64);
        den[qt] += __shfl_xor(den[qt], 32, 64);
    }

    const size_t pb = (size_t)(nh * KS + ks) * LQ;
    // numP layout [nh][ks][q][v32] -- v-contiguous for k3's coalesced reads
#pragma unroll
    for (int vt = 0; vt < 2; ++vt)
#pragma unroll
        for (int qt = 0; qt < 2; ++qt)
#pragma unroll
            for (int r = 0; r < 4; ++r)
                numP[(pb + qbase + qt * 16 + l15) * 32 + vt * 16 + quad * 4 + r]
                    = racc[vt][qt][r];

    if (lane < 16)
#pragma unroll
        for (int qt = 0; qt < 2; ++qt)
            denP[pb + qbase + qt * 16 + lane] = den[qt];
}

// ---------------------------------------------------------------------------
// Kernel 3: reduce partials -> R, fp32 SIMT output projection + residual.
// grid: 128 blocks = n(2) x 64 l-tiles of 64.  block: 256 thr = 4 waves.
// numP reads are v-contiguous (coalesced); Rf in LDS fp32.
// ---------------------------------------------------------------------------
__global__ __launch_bounds__(256) void k3_out(
        const float* __restrict__ numP, const float* __restrict__ denP,
        const float* __restrict__ Wm, const float* __restrict__ bm,
        const float* __restrict__ x, float* __restrict__ out) {
    const int tid  = threadIdx.x;
    const int lane = tid & 63;
    const int wv   = tid >> 6;
    const int n    = blockIdx.x >> 6;
    const int lt   = blockIdx.x & 63;
    const int l0   = lt * 64;

    __shared__ float Rf[64][65];    // [j = h*32+v][l], +1 pad
    __shared__ float dinv[2][64];

    // denominator reciprocals
    if (tid < 128) {
        const int hh = tid >> 6, li = tid & 63;
        float s = 0.f;
#pragma unroll
        for (int k = 0; k < KS; ++k)
            s += denP[(size_t)((n * 2 + hh) * KS + k) * LQ + l0 + li];
        dinv[hh][li] = 1.0f / s;
    }

    // reduce numP over ks: thread (v = tid&31, lsub = tid>>5) owns 2hh x 8l
    {
        const int v = tid & 31, lsub = tid >> 5;
#pragma unroll
        for (int hh = 0; hh < 2; ++hh) {
            const size_t base = (size_t)(n * 2 + hh) * KS * LQ;
#pragma unroll
            for (int i = 0; i < 8; ++i) {
                const int l = lsub + 8 * i;
                float s = 0.f;
#pragma unroll
                for (int k = 0; k < KS; ++k)
                    s += numP[(base + (size_t)k * LQ + l0 + l) * 32 + v];
                Rf[hh * 32 + v][l] = s;
            }
        }
    }
    __syncthreads();

    // projection: wave wv -> outputs o = wv*16..+15, lane = l
    const float d0 = dinv[0][lane], d1 = dinv[1][lane];
    float rj[64];
#pragma unroll
    for (int j = 0; j < 64; ++j)
        rj[j] = Rf[j][lane] * (j < 32 ? d0 : d1);

    float acc[16];
#pragma unroll
    for (int oi = 0; oi < 16; ++oi) acc[oi] = bm[wv * 16 + oi];
#pragma unroll
    for (int oi = 0; oi < 16; ++oi) {
        const float* wr = Wm + (size_t)(wv * 16 + oi) * 64;
        float a = acc[oi];
#pragma unroll
        for (int j4 = 0; j4 < 16; ++j4) {
            f4_t t = *(const f4_t*)(wr + j4 * 4);   // wave-uniform -> s_load
            a = fmaf(t[0], rj[j4 * 4 + 0], a);
            a = fmaf(t[1], rj[j4 * 4 + 1], a);
            a = fmaf(t[2], rj[j4 * 4 + 2], a);
            a = fmaf(t[3], rj[j4 * 4 + 3], a);
        }
        acc[oi] = a;
    }

    // epilogue: + residual, coalesced fp32
#pragma unroll
    for (int oi = 0; oi < 16; ++oi) {
        const int o = wv * 16 + oi;
        const size_t idx = (size_t)(n * 64 + o) * LQ + l0 + lane;
        out[idx] = acc[oi] + x[idx];
    }
}

// ---------------------------------------------------------------------------
extern "C" void kernel_launch(void* const* d_in, const int* in_sizes, int n_in,
                              void* d_out, int out_size, void* d_ws, size_t ws_size,
                              hipStream_t stream) {
    const float* x  = (const float*)d_in[0];
    const float* Wq = (const float*)d_in[1];
    const float* bq = (const float*)d_in[2];
    const float* Wk = (const float*)d_in[3];
    const float* bk = (const float*)d_in[4];
    const float* Wv = (const float*)d_in[5];
    const float* bv = (const float*)d_in[6];
    const float* Wm = (const float*)d_in[7];
    const float* bm = (const float*)d_in[8];
    float* out = (float*)d_out;

    // workspace carve: Qb 2MB | Kb 2MB | Vtb 1MB | numP 16.8MB | denP 0.5MB
    __bf16* Qb  = (__bf16*)d_ws;
    __bf16* Kb  = Qb + (size_t)NH * LQ * 64;
    __bf16* Vtb = Kb + (size_t)NH * LQ * 64;
    float*  numP = (float*)(Vtb + (size_t)NH * 32 * LQ);
    float*  denP = numP + (size_t)NH * KS * 32 * LQ;

    k1_qkv<<<dim3(3, 64, 2), dim3(128), 0, stream>>>(x, Wq, bq, Wk, bk, Wv, bv,
                                                     Qb, Kb, Vtb);
    k2_attn<<<dim3(32, NH, KS), dim3(256), 0, stream>>>(Qb, Kb, Vtb, numP, denP);
    k3_out<<<dim3(128), dim3(256), 0, stream>>>(numP, denP, Wm, bm, x, out);
}

// Round 4
// 166.867 us; speedup vs baseline: 1.2420x; 1.2420x over previous
//
#include <hip/hip_runtime.h>
#include <cmath>

// MHSA cosine-attention block, MI355X/gfx950.  Round 4.
// K1: lane = output-channel. Weights w[64] fp32 in VGPRs (bounded live set,
//     no spill). x tile staged in LDS once (coalesced), compute reads are
//     same-address broadcasts. 5 waves: Qh0|Qh1|Kh0|Kh1|V. Norm = 64-lane
//     shuffle (lane = k). V transposed via LDS for coalesced b128 stores.
// K2: flash attention, S^T = K Q^T, packed ds_write_b64 P rows, 32 q/wave,
//     grid (32,4,8) = 4096 waves (4/SIMD @ launch_bounds(256,4)).  (as R3)
// K3: coalesced reduce of numP, fp32 SIMT output projection + residual. (as R3)

typedef __bf16 bf16x8 __attribute__((ext_vector_type(8)));
typedef __bf16 bf16x4 __attribute__((ext_vector_type(4)));
typedef float f4_t __attribute__((ext_vector_type(4)));

#define LQ 4096       // sequence length H*W
#define NH 4          // n*heads
#define KS 8          // key splits

__device__ inline f4_t mfma16(bf16x8 a, bf16x8 b, f4_t c) {
    return __builtin_amdgcn_mfma_f32_16x16x32_bf16(a, b, c, 0, 0, 0);
}

// ---------------------------------------------------------------------------
// Kernel 1: QKV projection + normalize.
// grid: dim3(128, 2) = l-tile(32) x n.  block: 320 thr = 5 waves.
// wave 0..3: lane = k, head = wave&1, Q if wave<2 else K. wave 4: lane = V row.
// ---------------------------------------------------------------------------
__global__ __launch_bounds__(320) void k1_qkv(
        const float* __restrict__ x,
        const float* __restrict__ Wq, const float* __restrict__ bq,
        const float* __restrict__ Wk, const float* __restrict__ bk,
        const float* __restrict__ Wv, const float* __restrict__ bv,
        __bf16* __restrict__ Qb, __bf16* __restrict__ Kb,
        __bf16* __restrict__ Vtb) {
    const int tid  = threadIdx.x;
    const int lane = tid & 63;
    const int wave = tid >> 6;
    const int lt   = blockIdx.x;
    const int n    = blockIdx.y;
    const int l0   = lt * 32;

    __shared__ float  xl[32][68];    // [l][c], pitch 68 floats (272B, 16B-aligned)
    __shared__ __bf16 Vl[64][40];    // V transpose staging

    // stage x tile: coalesced global, transposed into LDS
    if (tid < 256) {
        const int c = tid >> 5, l = tid & 31;
#pragma unroll
        for (int i = 0; i < 8; ++i)
            xl[l][c + i * 8] = x[((size_t)n * 64 + c + i * 8) * LQ + l0 + l];
    }
    __syncthreads();

    // per-lane weight row (64 fp32 in VGPRs) + bias
    const float* wrow;
    float bias;
    const int h = wave & 1;
    if (wave < 2)      { wrow = Wq + (size_t)(h * 64 + lane) * 64; bias = bq[h * 64 + lane]; }
    else if (wave < 4) { wrow = Wk + (size_t)(h * 64 + lane) * 64; bias = bk[h * 64 + lane]; }
    else               { wrow = Wv + (size_t)lane * 64;            bias = bv[lane]; }

    float w[64];
#pragma unroll
    for (int c4 = 0; c4 < 16; ++c4) {
        f4_t t = *(const f4_t*)(wrow + c4 * 4);
        w[c4 * 4 + 0] = t[0]; w[c4 * 4 + 1] = t[1];
        w[c4 * 4 + 2] = t[2]; w[c4 * 4 + 3] = t[3];
    }

    const int nh = n * 2 + h;
    __bf16* dst  = (wave < 2) ? Qb : Kb;
    const int kc = lane >> 3, kj = lane & 7;

#pragma unroll
    for (int lg = 0; lg < 8; ++lg) {
        float a0 = bias, a1 = bias, a2 = bias, a3 = bias;   // 4 independent l's
#pragma unroll
        for (int c4 = 0; c4 < 16; ++c4) {
            f4_t x0 = *(const f4_t*)&xl[lg * 4 + 0][c4 * 4];   // broadcast reads
            f4_t x1 = *(const f4_t*)&xl[lg * 4 + 1][c4 * 4];
            f4_t x2 = *(const f4_t*)&xl[lg * 4 + 2][c4 * 4];
            f4_t x3 = *(const f4_t*)&xl[lg * 4 + 3][c4 * 4];
#pragma unroll
            for (int j = 0; j < 4; ++j) {
                const float wc = w[c4 * 4 + j];
                a0 = fmaf(wc, x0[j], a0);
                a1 = fmaf(wc, x1[j], a1);
                a2 = fmaf(wc, x2[j], a2);
                a3 = fmaf(wc, x3[j], a3);
            }
        }
        float av[4] = {a0, a1, a2, a3};
        if (wave < 4) {
            // L2 norm across 64 lanes (= dk) per l, then k8-tiled bf16 store
#pragma unroll
            for (int u = 0; u < 4; ++u) {
                float ss = av[u] * av[u];
#pragma unroll
                for (int m = 1; m < 64; m <<= 1) ss += __shfl_xor(ss, m, 64);
                const float val = av[u] / fmaxf(sqrtf(ss), 1e-6f);
                const int l = l0 + lg * 4 + u;
                dst[((size_t)(nh * 8 + kc) * LQ + l) * 8 + kj] = (__bf16)val;
            }
        } else {
#pragma unroll
            for (int u = 0; u < 4; ++u) Vl[lane][lg * 4 + u] = (__bf16)av[u];
        }
    }

    // V wave: coalesced transpose-out (rows are contiguous bf16)
    if (wave == 4) {
#pragma unroll
        for (int j = 0; j < 4; ++j) {
            bf16x8 t = *(const bf16x8*)&Vl[lane][j * 8];
            *(bf16x8*)(Vtb + ((size_t)n * 64 + lane) * LQ + l0 + j * 8) = t;
        }
    }
}

// ---------------------------------------------------------------------------
// Kernel 2: flash attention (scores in [-1,1], no max tracking).
// grid: (32 q-blocks of 128, nh=4, ks=8) = 1024 blocks x 4 waves = 4096 waves.
// S^T = K Q^T  =>  C lane holds 4 consecutive KEYS for one q  =>  P row
// writes pack to ds_write_b64; PV B-frag read is ds_read_b128.
// ---------------------------------------------------------------------------
__global__ __launch_bounds__(256, 4) void k2_attn(
        const __bf16* __restrict__ Qb, const __bf16* __restrict__ Kb,
        const __bf16* __restrict__ Vtb,
        float* __restrict__ numP, float* __restrict__ denP) {
    const int lane = threadIdx.x & 63;
    const int wave = threadIdx.x >> 6;
    const int quad = lane >> 4;
    const int l15  = lane & 15;
    const int nh   = blockIdx.y;
    const int ks   = blockIdx.z;
    const int qbase = blockIdx.x * 128 + wave * 32;
    const int kbase = ks * 512;

    __shared__ __bf16 P[4][2][16][40];   // [wave][qt][q-row][32 keys + pad]

    const f4_t fzero = {0.f, 0.f, 0.f, 0.f};

    // Q fragments (k8-tiled layout), reused for all 512 keys
    bf16x8 qf[2][2];
#pragma unroll
    for (int qt = 0; qt < 2; ++qt)
#pragma unroll
        for (int kh = 0; kh < 2; ++kh)
            qf[qt][kh] = *(const bf16x8*)(Qb +
                ((size_t)(nh * 8 + kh * 4 + quad) * LQ + qbase + qt * 16 + l15) * 8);

    f4_t racc[2][2];                     // [vt][qt]: (v=quad*4+r+vt*16, q=l15+qt*16)
#pragma unroll
    for (int a = 0; a < 2; ++a)
#pragma unroll
        for (int b = 0; b < 2; ++b) racc[a][b] = fzero;
    float den[2] = {0.f, 0.f};

    for (int ch = 0; ch < 16; ++ch) {
        const int kb = kbase + ch * 32;

        bf16x8 kf[2][2], vf[2];
#pragma unroll
        for (int kt = 0; kt < 2; ++kt)
#pragma unroll
            for (int kh = 0; kh < 2; ++kh)
                kf[kt][kh] = *(const bf16x8*)(Kb +
                    ((size_t)(nh * 8 + kh * 4 + quad) * LQ + kb + kt * 16 + l15) * 8);
#pragma unroll
        for (int vt = 0; vt < 2; ++vt)
            vf[vt] = *(const bf16x8*)(Vtb +
                (size_t)(nh * 32 + vt * 16 + l15) * LQ + kb + quad * 8);

#pragma unroll
        for (int qt = 0; qt < 2; ++qt) {
#pragma unroll
            for (int kt = 0; kt < 2; ++kt) {
                // S^T tile: m = key (quad*4+r), n = q (l15)
                f4_t s = mfma16(kf[kt][0], qf[qt][0], fzero);
                s      = mfma16(kf[kt][1], qf[qt][1], s);
                bf16x4 pv;
                float d = 0.f;
#pragma unroll
                for (int r = 0; r < 4; ++r) {
                    float p = __expf(s[r]);
                    d += p;
                    pv[r] = (__bf16)p;
                }
                den[qt] += d;
                *(bf16x4*)&P[wave][qt][l15][kt * 16 + quad * 4] = pv;  // b64 packed
            }
            // PV: A = V^T rows (key-major), B = P rows (key-major)
            bf16x8 pf = *(const bf16x8*)&P[wave][qt][l15][quad * 8];   // b128
#pragma unroll
            for (int vt = 0; vt < 2; ++vt)
                racc[vt][qt] = mfma16(vf[vt], pf, racc[vt][qt]);
        }
    }

    // den: reduce quad partials (same q = l15 across quads)
#pragma unroll
    for (int qt = 0; qt < 2; ++qt) {
        den[qt] += __shfl_xor(den[qt], 16, 64);
        den[qt] += __shfl_xor(den[qt], 32, 64);
    }

    const size_t pb = (size_t)(nh * KS + ks) * LQ;
    // numP layout [nh][ks][q][v32] -- v-contiguous for k3's coalesced reads
#pragma unroll
    for (int vt = 0; vt < 2; ++vt)
#pragma unroll
        for (int qt = 0; qt < 2; ++qt)
#pragma unroll
            for (int r = 0; r < 4; ++r)
                numP[(pb + qbase + qt * 16 + l15) * 32 + vt * 16 + quad * 4 + r]
                    = racc[vt][qt][r];

    if (lane < 16)
#pragma unroll
        for (int qt = 0; qt < 2; ++qt)
            denP[pb + qbase + qt * 16 + lane] = den[qt];
}

// ---------------------------------------------------------------------------
// Kernel 3: reduce partials -> R, fp32 SIMT output projection + residual.
// grid: 128 blocks = n(2) x 64 l-tiles of 64.  block: 256 thr = 4 waves.
// ---------------------------------------------------------------------------
__global__ __launch_bounds__(256) void k3_out(
        const float* __restrict__ numP, const float* __restrict__ denP,
        const float* __restrict__ Wm, const float* __restrict__ bm,
        const float* __restrict__ x, float* __restrict__ out) {
    const int tid  = threadIdx.x;
    const int lane = tid & 63;
    const int wv   = tid >> 6;
    const int n    = blockIdx.x >> 6;
    const int lt   = blockIdx.x & 63;
    const int l0   = lt * 64;

    __shared__ float Rf[64][65];    // [j = h*32+v][l], +1 pad
    __shared__ float dinv[2][64];

    if (tid < 128) {
        const int hh = tid >> 6, li = tid & 63;
        float s = 0.f;
#pragma unroll
        for (int k = 0; k < KS; ++k)
            s += denP[(size_t)((n * 2 + hh) * KS + k) * LQ + l0 + li];
        dinv[hh][li] = 1.0f / s;
    }

    // reduce numP over ks: thread (v = tid&31, lsub = tid>>5) owns 2hh x 8l
    {
        const int v = tid & 31, lsub = tid >> 5;
#pragma unroll
        for (int hh = 0; hh < 2; ++hh) {
            const size_t base = (size_t)(n * 2 + hh) * KS * LQ;
#pragma unroll
            for (int i = 0; i < 8; ++i) {
                const int l = lsub + 8 * i;
                float s = 0.f;
#pragma unroll
                for (int k = 0; k < KS; ++k)
                    s += numP[(base + (size_t)k * LQ + l0 + l) * 32 + v];
                Rf[hh * 32 + v][l] = s;
            }
        }
    }
    __syncthreads();

    // projection: wave wv -> outputs o = wv*16..+15, lane = l
    const float d0 = dinv[0][lane], d1 = dinv[1][lane];
    float rj[64];
#pragma unroll
    for (int j = 0; j < 64; ++j)
        rj[j] = Rf[j][lane] * (j < 32 ? d0 : d1);

    float acc[16];
#pragma unroll
    for (int oi = 0; oi < 16; ++oi) acc[oi] = bm[wv * 16 + oi];
#pragma unroll
    for (int oi = 0; oi < 16; ++oi) {
        const float* wr = Wm + (size_t)(wv * 16 + oi) * 64;
        float a = acc[oi];
#pragma unroll
        for (int j4 = 0; j4 < 16; ++j4) {
            f4_t t = *(const f4_t*)(wr + j4 * 4);
            a = fmaf(t[0], rj[j4 * 4 + 0], a);
            a = fmaf(t[1], rj[j4 * 4 + 1], a);
            a = fmaf(t[2], rj[j4 * 4 + 2], a);
            a = fmaf(t[3], rj[j4 * 4 + 3], a);
        }
        acc[oi] = a;
    }

#pragma unroll
    for (int oi = 0; oi < 16; ++oi) {
        const int o = wv * 16 + oi;
        const size_t idx = (size_t)(n * 64 + o) * LQ + l0 + lane;
        out[idx] = acc[oi] + x[idx];
    }
}

// ---------------------------------------------------------------------------
extern "C" void kernel_launch(void* const* d_in, const int* in_sizes, int n_in,
                              void* d_out, int out_size, void* d_ws, size_t ws_size,
                              hipStream_t stream) {
    const float* x  = (const float*)d_in[0];
    const float* Wq = (const float*)d_in[1];
    const float* bq = (const float*)d_in[2];
    const float* Wk = (const float*)d_in[3];
    const float* bk = (const float*)d_in[4];
    const float* Wv = (const float*)d_in[5];
    const float* bv = (const float*)d_in[6];
    const float* Wm = (const float*)d_in[7];
    const float* bm = (const float*)d_in[8];
    float* out = (float*)d_out;

    // workspace carve: Qb 2MB | Kb 2MB | Vtb 1MB | numP 16.8MB | denP 0.5MB
    __bf16* Qb  = (__bf16*)d_ws;
    __bf16* Kb  = Qb + (size_t)NH * LQ * 64;
    __bf16* Vtb = Kb + (size_t)NH * LQ * 64;
    float*  numP = (float*)(Vtb + (size_t)NH * 32 * LQ);
    float*  denP = numP + (size_t)NH * KS * 32 * LQ;

    k1_qkv<<<dim3(128, 2), dim3(320), 0, stream>>>(x, Wq, bq, Wk, bk, Wv, bv,
                                                   Qb, Kb, Vtb);
    k2_attn<<<dim3(32, NH, KS), dim3(256), 0, stream>>>(Qb, Kb, Vtb, numP, denP);
    k3_out<<<dim3(128), dim3(256), 0, stream>>>(numP, denP, Wm, bm, x, out);
}

// Round 5
// 124.873 us; speedup vs baseline: 1.6597x; 1.3363x over previous
//
#include <hip/hip_runtime.h>
#include <cmath>

// MHSA cosine-attention block, MI355X/gfx950.  Round 5.
// K0: one-time prep -> Wb[320][64] bf16 (rows: Q128|K128|V64) + bb[320] fp32.
// K1: QKV projection as MFMA GEMM. Block stages 64c x 32l x-tile in LDS;
//     wave w = {Qh0,Qh1,Kh0,Kh1} rows w*64..+63 (+ V rows 256+w*16..+15).
//     L2 norm is within-wave (16 per-lane squares + shfl_xor 16/32).
//     Bounded register state -> no spill by construction.
// K2: flash attention, S^T = K Q^T, packed ds_write_b64 P rows, 32 q/wave,
//     grid (32,4,8) = 4096 waves.  (unchanged from R4)
// K3: coalesced reduce of numP, fp32 SIMT output projection + residual. (unchanged)

typedef __bf16 bf16x8 __attribute__((ext_vector_type(8)));
typedef __bf16 bf16x4 __attribute__((ext_vector_type(4)));
typedef float f4_t __attribute__((ext_vector_type(4)));

#define LQ 4096       // sequence length H*W
#define NH 4          // n*heads
#define KS 8          // key splits

__device__ inline f4_t mfma16(bf16x8 a, bf16x8 b, f4_t c) {
    return __builtin_amdgcn_mfma_f32_16x16x32_bf16(a, b, c, 0, 0, 0);
}

// ---------------------------------------------------------------------------
// Kernel 0: weight prep.  grid 5 x 256 thr; block g -> rows g*64..+63.
// Wb row order: 0-127 = Wq (h*64+k), 128-255 = Wk, 256-319 = Wv (h*32+v).
// ---------------------------------------------------------------------------
__global__ void k0_prep(const float* __restrict__ Wq, const float* __restrict__ bq,
                        const float* __restrict__ Wk, const float* __restrict__ bk,
                        const float* __restrict__ Wv, const float* __restrict__ bv,
                        __bf16* __restrict__ Wb, float* __restrict__ bb) {
    const int tid = threadIdx.x;
    const int row = blockIdx.x * 64 + (tid >> 2);
    const int c0  = (tid & 3) * 16;

    const float* wsrc;
    float bval;
    if (row < 128)      { wsrc = Wq + (size_t)row * 64;         bval = bq[row]; }
    else if (row < 256) { wsrc = Wk + (size_t)(row - 128) * 64; bval = bk[row - 128]; }
    else                { wsrc = Wv + (size_t)(row - 256) * 64; bval = bv[row - 256]; }

#pragma unroll
    for (int j = 0; j < 16; ++j)
        Wb[(size_t)row * 64 + c0 + j] = (__bf16)wsrc[c0 + j];
    if ((tid & 3) == 0) bb[row] = bval;
}

// ---------------------------------------------------------------------------
// Kernel 1: QKV projection + normalize via MFMA.
// grid: dim3(128, 2) = l-tile(32) x n.  block: 256 thr = 4 waves.
// ---------------------------------------------------------------------------
__global__ __launch_bounds__(256) void k1_qkv(
        const float* __restrict__ x,
        const __bf16* __restrict__ Wb, const float* __restrict__ bb,
        __bf16* __restrict__ Qb, __bf16* __restrict__ Kb,
        __bf16* __restrict__ Vtb) {
    const int tid  = threadIdx.x;
    const int lane = tid & 63;
    const int w    = tid >> 6;
    const int quad = lane >> 4;
    const int l15  = lane & 15;
    const int lt   = blockIdx.x;
    const int n    = blockIdx.y;
    const int l0   = lt * 32;

    __shared__ __bf16 xl[32][72];   // [l][c] bf16, pitch 72 (16B-aligned rows)

    // stage x tile (transpose to [l][c]): coalesced 128B global segments
    {
        const int c0 = tid >> 5, l = tid & 31;
#pragma unroll
        for (int i = 0; i < 8; ++i) {
            const int c = c0 + i * 8;
            xl[l][c] = (__bf16)x[((size_t)n * 64 + c) * LQ + l0 + l];
        }
    }

    // A fragments: Q/K rows w*64 + t*16 + l15, and V rows 256 + w*16 + l15
    bf16x8 af[4][2], av[2];
#pragma unroll
    for (int t = 0; t < 4; ++t)
#pragma unroll
        for (int kh = 0; kh < 2; ++kh)
            af[t][kh] = *(const bf16x8*)(Wb +
                (size_t)(w * 64 + t * 16 + l15) * 64 + kh * 32 + quad * 8);
#pragma unroll
    for (int kh = 0; kh < 2; ++kh)
        av[kh] = *(const bf16x8*)(Wb +
            (size_t)(256 + w * 16 + l15) * 64 + kh * 32 + quad * 8);

    // bias -> accumulator init values (per-lane rows quad*4+r)
    f4_t binit[4], bvinit;
#pragma unroll
    for (int t = 0; t < 4; ++t)
#pragma unroll
        for (int r = 0; r < 4; ++r)
            binit[t][r] = bb[w * 64 + t * 16 + quad * 4 + r];
#pragma unroll
    for (int r = 0; r < 4; ++r)
        bvinit[r] = bb[256 + w * 16 + quad * 4 + r];

    __syncthreads();

    // B fragments from LDS and the 20 MFMAs
    f4_t acc[4][2], vacc[2];
#pragma unroll
    for (int lsub = 0; lsub < 2; ++lsub) {
        bf16x8 bf0 = *(const bf16x8*)&xl[lsub * 16 + l15][quad * 8];
        bf16x8 bf1 = *(const bf16x8*)&xl[lsub * 16 + l15][32 + quad * 8];
#pragma unroll
        for (int t = 0; t < 4; ++t) {
            f4_t a = mfma16(af[t][0], bf0, binit[t]);
            acc[t][lsub] = mfma16(af[t][1], bf1, a);
        }
        f4_t va = mfma16(av[0], bf0, bvinit);
        vacc[lsub] = mfma16(av[1], bf1, va);
    }

    // epilogue: Q/K normalize + k8-tiled store
    const int nh = n * 2 + (w & 1);
    __bf16* dst  = (w < 2) ? Qb : Kb;
#pragma unroll
    for (int lsub = 0; lsub < 2; ++lsub) {
        float ss = 0.f;
#pragma unroll
        for (int t = 0; t < 4; ++t)
#pragma unroll
            for (int r = 0; r < 4; ++r)
                ss = fmaf(acc[t][lsub][r], acc[t][lsub][r], ss);
        ss += __shfl_xor(ss, 16, 64);
        ss += __shfl_xor(ss, 32, 64);
        const float rn = 1.0f / fmaxf(sqrtf(ss), 1e-6f);

        const int l = l0 + lsub * 16 + l15;
#pragma unroll
        for (int t = 0; t < 4; ++t) {
            bf16x4 pk;
#pragma unroll
            for (int r = 0; r < 4; ++r) pk[r] = (__bf16)(acc[t][lsub][r] * rn);
            const int kc = t * 2 + (quad >> 1);
            *(bf16x4*)(dst + ((size_t)(nh * 8 + kc) * LQ + l) * 8 + (quad & 1) * 4) = pk;
        }
        // V rows: vrow = w*16 + quad*4 + r  (n-local channel h*32+v)
#pragma unroll
        for (int r = 0; r < 4; ++r) {
            const int vrow = w * 16 + quad * 4 + r;
            Vtb[(size_t)(n * 64 + vrow) * LQ + l] = (__bf16)vacc[lsub][r];
        }
    }
}

// ---------------------------------------------------------------------------
// Kernel 2: flash attention (scores in [-1,1], no max tracking).
// grid: (32 q-blocks of 128, nh=4, ks=8) = 1024 blocks x 4 waves = 4096 waves.
// S^T = K Q^T  =>  C lane holds 4 consecutive KEYS for one q  =>  P row
// writes pack to ds_write_b64; PV B-frag read is ds_read_b128.
// ---------------------------------------------------------------------------
__global__ __launch_bounds__(256, 4) void k2_attn(
        const __bf16* __restrict__ Qb, const __bf16* __restrict__ Kb,
        const __bf16* __restrict__ Vtb,
        float* __restrict__ numP, float* __restrict__ denP) {
    const int lane = threadIdx.x & 63;
    const int wave = threadIdx.x >> 6;
    const int quad = lane >> 4;
    const int l15  = lane & 15;
    const int nh   = blockIdx.y;
    const int ks   = blockIdx.z;
    const int qbase = blockIdx.x * 128 + wave * 32;
    const int kbase = ks * 512;

    __shared__ __bf16 P[4][2][16][40];   // [wave][qt][q-row][32 keys + pad]

    const f4_t fzero = {0.f, 0.f, 0.f, 0.f};

    // Q fragments (k8-tiled layout), reused for all 512 keys
    bf16x8 qf[2][2];
#pragma unroll
    for (int qt = 0; qt < 2; ++qt)
#pragma unroll
        for (int kh = 0; kh < 2; ++kh)
            qf[qt][kh] = *(const bf16x8*)(Qb +
                ((size_t)(nh * 8 + kh * 4 + quad) * LQ + qbase + qt * 16 + l15) * 8);

    f4_t racc[2][2];                     // [vt][qt]: (v=quad*4+r+vt*16, q=l15+qt*16)
#pragma unroll
    for (int a = 0; a < 2; ++a)
#pragma unroll
        for (int b = 0; b < 2; ++b) racc[a][b] = fzero;
    float den[2] = {0.f, 0.f};

    for (int ch = 0; ch < 16; ++ch) {
        const int kb = kbase + ch * 32;

        bf16x8 kf[2][2], vf[2];
#pragma unroll
        for (int kt = 0; kt < 2; ++kt)
#pragma unroll
            for (int kh = 0; kh < 2; ++kh)
                kf[kt][kh] = *(const bf16x8*)(Kb +
                    ((size_t)(nh * 8 + kh * 4 + quad) * LQ + kb + kt * 16 + l15) * 8);
#pragma unroll
        for (int vt = 0; vt < 2; ++vt)
            vf[vt] = *(const bf16x8*)(Vtb +
                (size_t)(nh * 32 + vt * 16 + l15) * LQ + kb + quad * 8);

#pragma unroll
        for (int qt = 0; qt < 2; ++qt) {
#pragma unroll
            for (int kt = 0; kt < 2; ++kt) {
                // S^T tile: m = key (quad*4+r), n = q (l15)
                f4_t s = mfma16(kf[kt][0], qf[qt][0], fzero);
                s      = mfma16(kf[kt][1], qf[qt][1], s);
                bf16x4 pv;
                float d = 0.f;
#pragma unroll
                for (int r = 0; r < 4; ++r) {
                    float p = __expf(s[r]);
                    d += p;
                    pv[r] = (__bf16)p;
                }
                den[qt] += d;
                *(bf16x4*)&P[wave][qt][l15][kt * 16 + quad * 4] = pv;  // b64 packed
            }
            // PV: A = V^T rows (key-major), B = P rows (key-major)
            bf16x8 pf = *(const bf16x8*)&P[wave][qt][l15][quad * 8];   // b128
#pragma unroll
            for (int vt = 0; vt < 2; ++vt)
                racc[vt][qt] = mfma16(vf[vt], pf, racc[vt][qt]);
        }
    }

    // den: reduce quad partials (same q = l15 across quads)
#pragma unroll
    for (int qt = 0; qt < 2; ++qt) {
        den[qt] += __shfl_xor(den[qt], 16, 64);
        den[qt] += __shfl_xor(den[qt], 32, 64);
    }

    const size_t pb = (size_t)(nh * KS + ks) * LQ;
    // numP layout [nh][ks][q][v32] -- v-contiguous for k3's coalesced reads
#pragma unroll
    for (int vt = 0; vt < 2; ++vt)
#pragma unroll
        for (int qt = 0; qt < 2; ++qt)
#pragma unroll
            for (int r = 0; r < 4; ++r)
                numP[(pb + qbase + qt * 16 + l15) * 32 + vt * 16 + quad * 4 + r]
                    = racc[vt][qt][r];

    if (lane < 16)
#pragma unroll
        for (int qt = 0; qt < 2; ++qt)
            denP[pb + qbase + qt * 16 + lane] = den[qt];
}

// ---------------------------------------------------------------------------
// Kernel 3: reduce partials -> R, fp32 SIMT output projection + residual.
// grid: 128 blocks = n(2) x 64 l-tiles of 64.  block: 256 thr = 4 waves.
// ---------------------------------------------------------------------------
__global__ __launch_bounds__(256) void k3_out(
        const float* __restrict__ numP, const float* __restrict__ denP,
        const float* __restrict__ Wm, const float* __restrict__ bm,
        const float* __restrict__ x, float* __restrict__ out) {
    const int tid  = threadIdx.x;
    const int lane = tid & 63;
    const int wv   = tid >> 6;
    const int n    = blockIdx.x >> 6;
    const int lt   = blockIdx.x & 63;
    const int l0   = lt * 64;

    __shared__ float Rf[64][65];    // [j = h*32+v][l], +1 pad
    __shared__ float dinv[2][64];

    if (tid < 128) {
        const int hh = tid >> 6, li = tid & 63;
        float s = 0.f;
#pragma unroll
        for (int k = 0; k < KS; ++k)
            s += denP[(size_t)((n * 2 + hh) * KS + k) * LQ + l0 + li];
        dinv[hh][li] = 1.0f / s;
    }

    // reduce numP over ks: thread (v = tid&31, lsub = tid>>5) owns 2hh x 8l
    {
        const int v = tid & 31, lsub = tid >> 5;
#pragma unroll
        for (int hh = 0; hh < 2; ++hh) {
            const size_t base = (size_t)(n * 2 + hh) * KS * LQ;
#pragma unroll
            for (int i = 0; i < 8; ++i) {
                const int l = lsub + 8 * i;
                float s = 0.f;
#pragma unroll
                for (int k = 0; k < KS; ++k)
                    s += numP[(base + (size_t)k * LQ + l0 + l) * 32 + v];
                Rf[hh * 32 + v][l] = s;
            }
        }
    }
    __syncthreads();

    // projection: wave wv -> outputs o = wv*16..+15, lane = l
    const float d0 = dinv[0][lane], d1 = dinv[1][lane];
    float rj[64];
#pragma unroll
    for (int j = 0; j < 64; ++j)
        rj[j] = Rf[j][lane] * (j < 32 ? d0 : d1);

    float acc[16];
#pragma unroll
    for (int oi = 0; oi < 16; ++oi) acc[oi] = bm[wv * 16 + oi];
#pragma unroll
    for (int oi = 0; oi < 16; ++oi) {
        const float* wr = Wm + (size_t)(wv * 16 + oi) * 64;
        float a = acc[oi];
#pragma unroll
        for (int j4 = 0; j4 < 16; ++j4) {
            f4_t t = *(const f4_t*)(wr + j4 * 4);
            a = fmaf(t[0], rj[j4 * 4 + 0], a);
            a = fmaf(t[1], rj[j4 * 4 + 1], a);
            a = fmaf(t[2], rj[j4 * 4 + 2], a);
            a = fmaf(t[3], rj[j4 * 4 + 3], a);
        }
        acc[oi] = a;
    }

#pragma unroll
    for (int oi = 0; oi < 16; ++oi) {
        const int o = wv * 16 + oi;
        const size_t idx = (size_t)(n * 64 + o) * LQ + l0 + lane;
        out[idx] = acc[oi] + x[idx];
    }
}

// ---------------------------------------------------------------------------
extern "C" void kernel_launch(void* const* d_in, const int* in_sizes, int n_in,
                              void* d_out, int out_size, void* d_ws, size_t ws_size,
                              hipStream_t stream) {
    const float* x  = (const float*)d_in[0];
    const float* Wq = (const float*)d_in[1];
    const float* bq = (const float*)d_in[2];
    const float* Wk = (const float*)d_in[3];
    const float* bk = (const float*)d_in[4];
    const float* Wv = (const float*)d_in[5];
    const float* bv = (const float*)d_in[6];
    const float* Wm = (const float*)d_in[7];
    const float* bm = (const float*)d_in[8];
    float* out = (float*)d_out;

    // workspace carve: Qb 2MB | Kb 2MB | Vtb 1MB | numP 16.8MB | denP 0.5MB | Wb 40KB | bb 1.3KB
    __bf16* Qb  = (__bf16*)d_ws;
    __bf16* Kb  = Qb + (size_t)NH * LQ * 64;
    __bf16* Vtb = Kb + (size_t)NH * LQ * 64;
    float*  numP = (float*)(Vtb + (size_t)NH * 32 * LQ);
    float*  denP = numP + (size_t)NH * KS * 32 * LQ;
    __bf16* Wb  = (__bf16*)(denP + (size_t)NH * KS * LQ);
    float*  bb  = (float*)(Wb + 320 * 64);

    k0_prep<<<dim3(5), dim3(256), 0, stream>>>(Wq, bq, Wk, bk, Wv, bv, Wb, bb);
    k1_qkv<<<dim3(128, 2), dim3(256), 0, stream>>>(x, Wb, bb, Qb, Kb, Vtb);
    k2_attn<<<dim3(32, NH, KS), dim3(256), 0, stream>>>(Qb, Kb, Vtb, numP, denP);
    k3_out<<<dim3(128), dim3(256), 0, stream>>>(numP, denP, Wm, bm, x, out);
}

// Round 6
// 120.615 us; speedup vs baseline: 1.7183x; 1.0353x over previous
//
#include <hip/hip_runtime.h>
#include <cmath>

// MHSA cosine-attention block, MI355X/gfx950.  Round 6.
// K0: one-time prep -> Wb[320][64] bf16 (rows: Q128|K128|V64) + bb[320] fp32.
// K1: QKV projection as MFMA GEMM (unchanged from R5).
// K2: flash attention v3: K chunk staged ONCE per block in LDS (double-
//     buffered, shuffled layout -> both staging writes and frag reads are
//     contiguous b128 per wave, conflict-free). V direct from L2.
//     all-S -> exp -> P LDS round trip -> all-PV per chunk.
// K3: coalesced reduce of numP, fp32 SIMT output projection + residual.

typedef __bf16 bf16x8 __attribute__((ext_vector_type(8)));
typedef __bf16 bf16x4 __attribute__((ext_vector_type(4)));
typedef float f4_t __attribute__((ext_vector_type(4)));

#define LQ 4096       // sequence length H*W
#define NH 4          // n*heads
#define KS 8          // key splits

__device__ inline f4_t mfma16(bf16x8 a, bf16x8 b, f4_t c) {
    return __builtin_amdgcn_mfma_f32_16x16x32_bf16(a, b, c, 0, 0, 0);
}

// ---------------------------------------------------------------------------
// Kernel 0: weight prep.  grid 5 x 256 thr; block g -> rows g*64..+63.
// Wb row order: 0-127 = Wq (h*64+k), 128-255 = Wk, 256-319 = Wv (h*32+v).
// ---------------------------------------------------------------------------
__global__ void k0_prep(const float* __restrict__ Wq, const float* __restrict__ bq,
                        const float* __restrict__ Wk, const float* __restrict__ bk,
                        const float* __restrict__ Wv, const float* __restrict__ bv,
                        __bf16* __restrict__ Wb, float* __restrict__ bb) {
    const int tid = threadIdx.x;
    const int row = blockIdx.x * 64 + (tid >> 2);
    const int c0  = (tid & 3) * 16;

    const float* wsrc;
    float bval;
    if (row < 128)      { wsrc = Wq + (size_t)row * 64;         bval = bq[row]; }
    else if (row < 256) { wsrc = Wk + (size_t)(row - 128) * 64; bval = bk[row - 128]; }
    else                { wsrc = Wv + (size_t)(row - 256) * 64; bval = bv[row - 256]; }

#pragma unroll
    for (int j = 0; j < 16; ++j)
        Wb[(size_t)row * 64 + c0 + j] = (__bf16)wsrc[c0 + j];
    if ((tid & 3) == 0) bb[row] = bval;
}

// ---------------------------------------------------------------------------
// Kernel 1: QKV projection + normalize via MFMA.
// grid: dim3(128, 2) = l-tile(32) x n.  block: 256 thr = 4 waves.
// ---------------------------------------------------------------------------
__global__ __launch_bounds__(256) void k1_qkv(
        const float* __restrict__ x,
        const __bf16* __restrict__ Wb, const float* __restrict__ bb,
        __bf16* __restrict__ Qb, __bf16* __restrict__ Kb,
        __bf16* __restrict__ Vtb) {
    const int tid  = threadIdx.x;
    const int lane = tid & 63;
    const int w    = tid >> 6;
    const int quad = lane >> 4;
    const int l15  = lane & 15;
    const int lt   = blockIdx.x;
    const int n    = blockIdx.y;
    const int l0   = lt * 32;

    __shared__ __bf16 xl[32][72];   // [l][c] bf16, pitch 72 (16B-aligned rows)

    // stage x tile (transpose to [l][c]): coalesced 128B global segments
    {
        const int c0 = tid >> 5, l = tid & 31;
#pragma unroll
        for (int i = 0; i < 8; ++i) {
            const int c = c0 + i * 8;
            xl[l][c] = (__bf16)x[((size_t)n * 64 + c) * LQ + l0 + l];
        }
    }

    // A fragments: Q/K rows w*64 + t*16 + l15, and V rows 256 + w*16 + l15
    bf16x8 af[4][2], av[2];
#pragma unroll
    for (int t = 0; t < 4; ++t)
#pragma unroll
        for (int kh = 0; kh < 2; ++kh)
            af[t][kh] = *(const bf16x8*)(Wb +
                (size_t)(w * 64 + t * 16 + l15) * 64 + kh * 32 + quad * 8);
#pragma unroll
    for (int kh = 0; kh < 2; ++kh)
        av[kh] = *(const bf16x8*)(Wb +
            (size_t)(256 + w * 16 + l15) * 64 + kh * 32 + quad * 8);

    // bias -> accumulator init values (per-lane rows quad*4+r)
    f4_t binit[4], bvinit;
#pragma unroll
    for (int t = 0; t < 4; ++t)
#pragma unroll
        for (int r = 0; r < 4; ++r)
            binit[t][r] = bb[w * 64 + t * 16 + quad * 4 + r];
#pragma unroll
    for (int r = 0; r < 4; ++r)
        bvinit[r] = bb[256 + w * 16 + quad * 4 + r];

    __syncthreads();

    // B fragments from LDS and the 20 MFMAs
    f4_t acc[4][2], vacc[2];
#pragma unroll
    for (int lsub = 0; lsub < 2; ++lsub) {
        bf16x8 bf0 = *(const bf16x8*)&xl[lsub * 16 + l15][quad * 8];
        bf16x8 bf1 = *(const bf16x8*)&xl[lsub * 16 + l15][32 + quad * 8];
#pragma unroll
        for (int t = 0; t < 4; ++t) {
            f4_t a = mfma16(af[t][0], bf0, binit[t]);
            acc[t][lsub] = mfma16(af[t][1], bf1, a);
        }
        f4_t va = mfma16(av[0], bf0, bvinit);
        vacc[lsub] = mfma16(av[1], bf1, va);
    }

    // epilogue: Q/K normalize + k8-tiled store
    const int nh = n * 2 + (w & 1);
    __bf16* dst  = (w < 2) ? Qb : Kb;
#pragma unroll
    for (int lsub = 0; lsub < 2; ++lsub) {
        float ss = 0.f;
#pragma unroll
        for (int t = 0; t < 4; ++t)
#pragma unroll
            for (int r = 0; r < 4; ++r)
                ss = fmaf(acc[t][lsub][r], acc[t][lsub][r], ss);
        ss += __shfl_xor(ss, 16, 64);
        ss += __shfl_xor(ss, 32, 64);
        const float rn = 1.0f / fmaxf(sqrtf(ss), 1e-6f);

        const int l = l0 + lsub * 16 + l15;
#pragma unroll
        for (int t = 0; t < 4; ++t) {
            bf16x4 pk;
#pragma unroll
            for (int r = 0; r < 4; ++r) pk[r] = (__bf16)(acc[t][lsub][r] * rn);
            const int kc = t * 2 + (quad >> 1);
            *(bf16x4*)(dst + ((size_t)(nh * 8 + kc) * LQ + l) * 8 + (quad & 1) * 4) = pk;
        }
        // V rows: vrow = w*16 + quad*4 + r  (n-local channel h*32+v)
#pragma unroll
        for (int r = 0; r < 4; ++r) {
            const int vrow = w * 16 + quad * 4 + r;
            Vtb[(size_t)(n * 64 + vrow) * LQ + l] = (__bf16)vacc[lsub][r];
        }
    }
}

// ---------------------------------------------------------------------------
// Kernel 2: flash attention v3 (scores in [-1,1], no max tracking).
// grid: (32 q-blocks of 128, nh=4, ks=8) = 1024 blocks x 4 waves.
// K chunk (32 keys x 64 dk = 4 KB) staged per block in LDS, double-buffered.
// Shuffled LDS slot map: slot t <-> (kc = ((t>>6)&1)*4 + ((t>>4)&3),
//                                   l  = ((t>>7)<<4)  | (t&15))
// => staging write (lane t, slot t) AND frag read (kt,kh: slots
//    kt*128+kh*64+quad*16+l15) are both contiguous 1 KB per wave.
// ---------------------------------------------------------------------------
__global__ __launch_bounds__(256, 4) void k2_attn(
        const __bf16* __restrict__ Qb, const __bf16* __restrict__ Kb,
        const __bf16* __restrict__ Vtb,
        float* __restrict__ numP, float* __restrict__ denP) {
    const int tid  = threadIdx.x;
    const int lane = tid & 63;
    const int wave = tid >> 6;
    const int quad = lane >> 4;
    const int l15  = lane & 15;
    const int nh   = blockIdx.y;
    const int ks   = blockIdx.z;
    const int qbase = blockIdx.x * 128 + wave * 32;
    const int kbase = ks * 512;

    __shared__ __bf16 Kl[2][2048];       // 2 x 4 KB staged K chunks
    __shared__ __bf16 P[4][2][16][40];   // [wave][qt][q-row][32 keys + pad]

    const f4_t fzero = {0.f, 0.f, 0.f, 0.f};

    // staging slot -> source (kc, l) for this thread (constant per thread)
    const int s_kc = ((tid >> 6) & 1) * 4 + ((tid >> 4) & 3);
    const int s_l  = ((tid >> 7) << 4) | (tid & 15);
    const __bf16* s_src = Kb + ((size_t)(nh * 8 + s_kc) * LQ + kbase + s_l) * 8;

    // Q fragments (k8-tiled layout), reused for all 512 keys
    bf16x8 qf[2][2];
#pragma unroll
    for (int qt = 0; qt < 2; ++qt)
#pragma unroll
        for (int kh = 0; kh < 2; ++kh)
            qf[qt][kh] = *(const bf16x8*)(Qb +
                ((size_t)(nh * 8 + kh * 4 + quad) * LQ + qbase + qt * 16 + l15) * 8);

    f4_t racc[2][2];                     // [vt][qt]
#pragma unroll
    for (int a = 0; a < 2; ++a)
#pragma unroll
        for (int b = 0; b < 2; ++b) racc[a][b] = fzero;
    float den[2] = {0.f, 0.f};

    // stage chunk 0 into buffer 0
    *(bf16x8*)&Kl[0][tid * 8] = *(const bf16x8*)s_src;
    __syncthreads();

    for (int ch = 0; ch < 16; ++ch) {
        const int cur = ch & 1;

        // stage next chunk into the other buffer (overlaps this chunk's compute)
        if (ch < 15)
            *(bf16x8*)&Kl[cur ^ 1][tid * 8] =
                *(const bf16x8*)(s_src + (size_t)(ch + 1) * 32 * 8);

        const int kb = kbase + ch * 32;

        // V fragments direct from L2
        bf16x8 vf[2];
#pragma unroll
        for (int vt = 0; vt < 2; ++vt)
            vf[vt] = *(const bf16x8*)(Vtb +
                (size_t)(nh * 32 + vt * 16 + l15) * LQ + kb + quad * 8);

        // K fragments from staged LDS (contiguous 1 KB per wave-read)
        bf16x8 kf[2][2];
#pragma unroll
        for (int kt = 0; kt < 2; ++kt)
#pragma unroll
            for (int kh = 0; kh < 2; ++kh)
                kf[kt][kh] = *(const bf16x8*)
                    &Kl[cur][(kt * 128 + kh * 64 + quad * 16 + l15) * 8];

        // --- all S tiles ---
        f4_t s[2][2];
#pragma unroll
        for (int qt = 0; qt < 2; ++qt)
#pragma unroll
            for (int kt = 0; kt < 2; ++kt) {
                f4_t t = mfma16(kf[kt][0], qf[qt][0], fzero);
                s[qt][kt] = mfma16(kf[kt][1], qf[qt][1], t);
            }

        // --- exp + pack + den + P writes ---
#pragma unroll
        for (int qt = 0; qt < 2; ++qt)
#pragma unroll
            for (int kt = 0; kt < 2; ++kt) {
                bf16x4 pv;
                float d = 0.f;
#pragma unroll
                for (int r = 0; r < 4; ++r) {
                    float p = __expf(s[qt][kt][r]);
                    d += p;
                    pv[r] = (__bf16)p;
                }
                den[qt] += d;
                *(bf16x4*)&P[wave][qt][l15][kt * 16 + quad * 4] = pv;
            }

        // --- all PV tiles ---
#pragma unroll
        for (int qt = 0; qt < 2; ++qt) {
            bf16x8 pf = *(const bf16x8*)&P[wave][qt][l15][quad * 8];
#pragma unroll
            for (int vt = 0; vt < 2; ++vt)
                racc[vt][qt] = mfma16(vf[vt], pf, racc[vt][qt]);
        }

        __syncthreads();   // next-buffer staging complete + cur free to overwrite
    }

    // den: reduce quad partials (same q = l15 across quads)
#pragma unroll
    for (int qt = 0; qt < 2; ++qt) {
        den[qt] += __shfl_xor(den[qt], 16, 64);
        den[qt] += __shfl_xor(den[qt], 32, 64);
    }

    const size_t pb = (size_t)(nh * KS + ks) * LQ;
    // numP layout [nh][ks][q][v32] -- v-contiguous for k3's coalesced reads
#pragma unroll
    for (int vt = 0; vt < 2; ++vt)
#pragma unroll
        for (int qt = 0; qt < 2; ++qt)
#pragma unroll
            for (int r = 0; r < 4; ++r)
                numP[(pb + qbase + qt * 16 + l15) * 32 + vt * 16 + quad * 4 + r]
                    = racc[vt][qt][r];

    if (lane < 16)
#pragma unroll
        for (int qt = 0; qt < 2; ++qt)
            denP[pb + qbase + qt * 16 + lane] = den[qt];
}

// ---------------------------------------------------------------------------
// Kernel 3: reduce partials -> R, fp32 SIMT output projection + residual.
// grid: 128 blocks = n(2) x 64 l-tiles of 64.  block: 256 thr = 4 waves.
// ---------------------------------------------------------------------------
__global__ __launch_bounds__(256) void k3_out(
        const float* __restrict__ numP, const float* __restrict__ denP,
        const float* __restrict__ Wm, const float* __restrict__ bm,
        const float* __restrict__ x, float* __restrict__ out) {
    const int tid  = threadIdx.x;
    const int lane = tid & 63;
    const int wv   = tid >> 6;
    const int n    = blockIdx.x >> 6;
    const int lt   = blockIdx.x & 63;
    const int l0   = lt * 64;

    __shared__ float Rf[64][65];    // [j = h*32+v][l], +1 pad
    __shared__ float dinv[2][64];

    if (tid < 128) {
        const int hh = tid >> 6, li = tid & 63;
        float s = 0.f;
#pragma unroll
        for (int k = 0; k < KS; ++k)
            s += denP[(size_t)((n * 2 + hh) * KS + k) * LQ + l0 + li];
        dinv[hh][li] = 1.0f / s;
    }

    // reduce numP over ks: thread (v = tid&31, lsub = tid>>5) owns 2hh x 8l
    {
        const int v = tid & 31, lsub = tid >> 5;
#pragma unroll
        for (int hh = 0; hh < 2; ++hh) {
            const size_t base = (size_t)(n * 2 + hh) * KS * LQ;
#pragma unroll
            for (int i = 0; i < 8; ++i) {
                const int l = lsub + 8 * i;
                float s = 0.f;
#pragma unroll
                for (int k = 0; k < KS; ++k)
                    s += numP[(base + (size_t)k * LQ + l0 + l) * 32 + v];
                Rf[hh * 32 + v][l] = s;
            }
        }
    }
    __syncthreads();

    // projection: wave wv -> outputs o = wv*16..+15, lane = l
    const float d0 = dinv[0][lane], d1 = dinv[1][lane];
    float rj[64];
#pragma unroll
    for (int j = 0; j < 64; ++j)
        rj[j] = Rf[j][lane] * (j < 32 ? d0 : d1);

    float acc[16];
#pragma unroll
    for (int oi = 0; oi < 16; ++oi) acc[oi] = bm[wv * 16 + oi];
#pragma unroll
    for (int oi = 0; oi < 16; ++oi) {
        const float* wr = Wm + (size_t)(wv * 16 + oi) * 64;
        float a = acc[oi];
#pragma unroll
        for (int j4 = 0; j4 < 16; ++j4) {
            f4_t t = *(const f4_t*)(wr + j4 * 4);
            a = fmaf(t[0], rj[j4 * 4 + 0], a);
            a = fmaf(t[1], rj[j4 * 4 + 1], a);
            a = fmaf(t[2], rj[j4 * 4 + 2], a);
            a = fmaf(t[3], rj[j4 * 4 + 3], a);
        }
        acc[oi] = a;
    }

#pragma unroll
    for (int oi = 0; oi < 16; ++oi) {
        const int o = wv * 16 + oi;
        const size_t idx = (size_t)(n * 64 + o) * LQ + l0 + lane;
        out[idx] = acc[oi] + x[idx];
    }
}

// ---------------------------------------------------------------------------
extern "C" void kernel_launch(void* const* d_in, const int* in_sizes, int n_in,
                              void* d_out, int out_size, void* d_ws, size_t ws_size,
                              hipStream_t stream) {
    const float* x  = (const float*)d_in[0];
    const float* Wq = (const float*)d_in[1];
    const float* bq = (const float*)d_in[2];
    const float* Wk = (const float*)d_in[3];
    const float* bk = (const float*)d_in[4];
    const float* Wv = (const float*)d_in[5];
    const float* bv = (const float*)d_in[6];
    const float* Wm = (const float*)d_in[7];
    const float* bm = (const float*)d_in[8];
    float* out = (float*)d_out;

    // workspace carve: Qb 2MB | Kb 2MB | Vtb 1MB | numP 16.8MB | denP 0.5MB | Wb 40KB | bb
    __bf16* Qb  = (__bf16*)d_ws;
    __bf16* Kb  = Qb + (size_t)NH * LQ * 64;
    __bf16* Vtb = Kb + (size_t)NH * LQ * 64;
    float*  numP = (float*)(Vtb + (size_t)NH * 32 * LQ);
    float*  denP = numP + (size_t)NH * KS * 32 * LQ;
    __bf16* Wb  = (__bf16*)(denP + (size_t)NH * KS * LQ);
    float*  bb  = (float*)(Wb + 320 * 64);

    k0_prep<<<dim3(5), dim3(256), 0, stream>>>(Wq, bq, Wk, bk, Wv, bv, Wb, bb);
    k1_qkv<<<dim3(128, 2), dim3(256), 0, stream>>>(x, Wb, bb, Qb, Kb, Vtb);
    k2_attn<<<dim3(32, NH, KS), dim3(256), 0, stream>>>(Qb, Kb, Vtb, numP, denP);
    k3_out<<<dim3(128), dim3(256), 0, stream>>>(numP, denP, Wm, bm, x, out);
}